// Round 19
// baseline (259.937 us; speedup 1.0000x reference)
//
#include <hip/hip_runtime.h>
#include <hip/hip_bf16.h>

// Problem dims
#define NB 2
#define NL 2048
#define ND 1024
#define NH 16
#define NDK 64

typedef float fx4 __attribute__((ext_vector_type(4)));
typedef short sx8 __attribute__((ext_vector_type(8)));
typedef short sx4 __attribute__((ext_vector_type(4)));

static __device__ __forceinline__ short f2bf(float x) {
  __hip_bfloat16 h = __float2bfloat16(x);
  short s;
  __builtin_memcpy(&s, &h, 2);
  return s;
}

static __device__ __forceinline__ float bf2f(short s) {
  unsigned u = ((unsigned)(unsigned short)s) << 16;
  float f;
  __builtin_memcpy(&f, &u, 4);
  return f;
}

// 2^x via the HW transcendental unit
static __device__ __forceinline__ float ex2(float x) {
  float r; asm("v_exp_f32 %0, %1" : "=v"(r) : "v"(x)); return r;
}

// Barrier without vmcnt drain (LDS ordering only).
static __device__ __forceinline__ void lds_barrier() {
  __asm__ volatile("s_waitcnt lgkmcnt(0)" ::: "memory");
  __builtin_amdgcn_s_barrier();
}

// ---------------------------------------------------------------------------
// Transpose+cast: W[k][n] f32 -> WT[n][k] bf16 for Wq,Wk,Wv,Wfc.
// Wq additionally folds the (1/sqrt(dk))*log2(e) softmax scale.
// grid (16,16,4), block 256
// ---------------------------------------------------------------------------
__global__ __launch_bounds__(256) void wt_kernel(
    const float* __restrict__ Wq, const float* __restrict__ Wk,
    const float* __restrict__ Wv, const float* __restrict__ Wfc,
    short* __restrict__ wt)
{
  const float* W = (blockIdx.z==0)?Wq:(blockIdx.z==1)?Wk:(blockIdx.z==2)?Wv:Wfc;
  float sc = (blockIdx.z==0) ? 0.18033688011112042f : 1.0f;
  short* out = wt + (size_t)blockIdx.z*1024*1024;
  int n0 = blockIdx.x*64, k0 = blockIdx.y*64;
  __shared__ float t[64][65];
  int tid = threadIdx.x;
  int kr = tid>>2, ns = (tid&3)*16;
  #pragma unroll
  for (int i=0;i<4;i++){
    fx4 v = *(const fx4*)(W + (size_t)(k0+kr)*1024 + n0 + ns + i*4);
    t[kr][ns+i*4+0]=v[0]; t[kr][ns+i*4+1]=v[1];
    t[kr][ns+i*4+2]=v[2]; t[kr][ns+i*4+3]=v[3];
  }
  __syncthreads();
  int nr = tid>>2, ks = (tid&3)*16;
  sx8 o0,o1;
  #pragma unroll
  for (int i=0;i<8;i++){ o0[i]=f2bf(t[ks+i][nr]*sc); o1[i]=f2bf(t[ks+8+i][nr]*sc); }
  *(sx8*)(out + (size_t)(n0+nr)*1024 + k0 + ks)     = o0;
  *(sx8*)(out + (size_t)(n0+nr)*1024 + k0 + ks + 8) = o1;
}

// ---------------------------------------------------------------------------
// cast_kernel: q/k/v f32 [4096][1024] -> bf16. grid (2048,3), block 256.
// ---------------------------------------------------------------------------
__global__ __launch_bounds__(256) void cast_kernel(
    const float* __restrict__ q, const float* __restrict__ k,
    const float* __restrict__ v, short* __restrict__ qb,
    short* __restrict__ kb, short* __restrict__ vb)
{
  const float* src = (blockIdx.y==0)?q:(blockIdx.y==1)?k:v;
  short* dst = (blockIdx.y==0)?qb:(blockIdx.y==1)?kb:vb;
  size_t base = ((size_t)blockIdx.x*256 + threadIdx.x)*8;
  fx4 a = *(const fx4*)(src+base), b = *(const fx4*)(src+base+4);
  sx8 o;
  o[0]=f2bf(a[0]); o[1]=f2bf(a[1]); o[2]=f2bf(a[2]); o[3]=f2bf(a[3]);
  o[4]=f2bf(b[0]); o[5]=f2bf(b[1]); o[6]=f2bf(b[2]); o[7]=f2bf(b[3]);
  *(sx8*)(dst+base) = o;
}

// ---------------------------------------------------------------------------
// GEMM: C[4096x1024] = A(bf16) @ WT^T, 128x128 tile, BK=64, m97 structure:
// global_load_lds width-16 both sides, linear LDS, 2-barrier loop.
// mode 0: A=qb -> QH bf16 [B,H,L,64] (scale pre-folded into wt)
// mode 1: A=kb -> KH bf16 [B,H,L,64]
// mode 2: A=vb -> VT bf16 [B,H,64,L]
// mode 3: A=ao -> preLN f32 = C + residual(q)
// grid (8, 32, nz), block 256 (4 waves, 2x2 of 64x64)
// ---------------------------------------------------------------------------
__global__ __launch_bounds__(256) void gemm_kernel(
    const short* __restrict__ qb, const short* __restrict__ kb,
    const short* __restrict__ vb, const short* __restrict__ ao,
    const float* __restrict__ q, const short* __restrict__ wt,
    short* __restrict__ qh, short* __restrict__ kh, short* __restrict__ vtb,
    float* __restrict__ preln, int mode_base)
{
  int mode = mode_base + blockIdx.z;
  const short* Ab = (mode==0)?qb:(mode==1)?kb:(mode==2)?vb:ao;
  const short* Bw = wt + (size_t)mode*1048576;
  int m0 = blockIdx.y*128, n0 = blockIdx.x*128;
  __shared__ short Al[128*64];
  __shared__ short Bl[128*64];
  int tid = threadIdx.x;
  int w = tid>>6, l = tid&63, lr = l>>4, lc = l&15;
  int wm = w>>1, wn = w&1;
  int grow = l>>3, gcol = (l&7)*8;          // granule lane mapping

  fx4 acc[4][4];
  #pragma unroll
  for (int i=0;i<4;i++)
    #pragma unroll
    for (int j=0;j<4;j++) acc[i][j] = (fx4)0.0f;

  for (int kb2=0; kb2<1024; kb2+=64) {
    #pragma unroll
    for (int p=0;p<4;p++){
      int rb = w*32 + p*8;
      __builtin_amdgcn_global_load_lds(
        (const __attribute__((address_space(1))) int*)(Ab + (size_t)(m0+rb+grow)*1024 + kb2 + gcol),
        (__attribute__((address_space(3))) int*)&Al[rb*64], 16, 0, 0);
      __builtin_amdgcn_global_load_lds(
        (const __attribute__((address_space(1))) int*)(Bw + (size_t)(n0+rb+grow)*1024 + kb2 + gcol),
        (__attribute__((address_space(3))) int*)&Bl[rb*64], 16, 0, 0);
    }
    __syncthreads();
    #pragma unroll
    for (int kk=0;kk<2;kk++){
      sx8 af[4], bfr[4];
      int oct = kk*4 + lr;
      #pragma unroll
      for (int i=0;i<4;i++){
        af[i]  = *(const sx8*)&Al[(wm*64 + i*16 + lc)*64 + oct*8];
        bfr[i] = *(const sx8*)&Bl[(wn*64 + i*16 + lc)*64 + oct*8];
      }
      #pragma unroll
      for (int i=0;i<4;i++)
        #pragma unroll
        for (int j=0;j<4;j++)
          acc[i][j] = __builtin_amdgcn_mfma_f32_16x16x32_bf16(af[i], bfr[j], acc[i][j], 0,0,0);
    }
    __syncthreads();
  }

  #pragma unroll
  for (int i=0;i<4;i++){
    int mrow0 = m0 + wm*64 + i*16 + lr*4;
    #pragma unroll
    for (int j=0;j<4;j++){
      int n = n0 + wn*64 + j*16 + lc;
      if (mode<=1) {
        short* dst = (mode==0)?qh:kh;
        int hh = n>>6, d = n&63;
        #pragma unroll
        for (int r=0;r<4;r++){
          int mr = mrow0 + r; int bb = mr>>11, lp = mr&2047;
          dst[((size_t)(bb*16+hh)*2048 + lp)*64 + d] = f2bf(acc[i][j][r]);
        }
      } else if (mode==2) {
        int hh = n>>6, d = n&63;
        int bb = mrow0>>11, lp = mrow0&2047;
        sx4 pv;
        #pragma unroll
        for (int r=0;r<4;r++) pv[r] = f2bf(acc[i][j][r]);
        *(sx4*)&vtb[((size_t)(bb*16+hh)*64 + d)*2048 + lp] = pv;
      } else {
        #pragma unroll
        for (int r=0;r<4;r++){
          int mr = mrow0 + r;
          preln[(size_t)mr*1024 + n] = acc[i][j][r] + q[(size_t)mr*1024 + n];
        }
      }
    }
  }
}

// ---------------------------------------------------------------------------
// Fused attention (R18 structure + METERED fill interleave): 1-D grid 1024,
// XCD-local bh mapping (lin&7 = XCD; 4 bh x 32 vq per XCD -> K/V L2-local).
// The masked-tail zero fill is issued as a resumable state machine, <=3
// store-instrs per pass-1 tile-iter (after the MFMAs, so K prefetch loads
// queue ahead) -> fill HBM time drains under pass-1 compute without
// starving K loads (R17's failure mode) and without competing with
// pass-2's P-store stream (R15/R18's cost). Remainder flushes after
// pass 1. Pass 2: P tiles in pst + PV + 256B-contiguous NT streams.
// grid (1024), block 256.
// ---------------------------------------------------------------------------
__global__ __launch_bounds__(256) void attn_kernel(
    const short* __restrict__ qh, const short* __restrict__ kh,
    const short* __restrict__ vt, short* __restrict__ ao,
    float* __restrict__ attn)
{
  int lin = blockIdx.x;
  int c = lin & 7, m = lin >> 3;
  int s = m >> 5, vq = m & 31;
  int bh = c*4 + s;
  int r8 = vq & 7, g = ((vq >> 3) + s) & 3;
  int qt = (g==0) ? r8 : (g==1) ? (15-r8) : (g==2) ? (16+r8) : (31-r8);
  int qbase = qt*64;
  int tid = threadIdx.x, w = tid>>6, l = tid&63, lr = l>>4, lc = l&15;
  int qrow0 = qbase + w*16;
  int qrow_l = qrow0 + lc;
  int kend = qrow0 + 16;

  float* arow = attn + (size_t)bh*NL*NL;
  const short* qhb = qh + (size_t)bh*NL*64;
  const short* khb = kh + (size_t)bh*NL*64;
  const short* vtb = vt + (size_t)bh*64*NL;

  sx8 Qf0 = *(const sx8*)&qhb[(size_t)qrow_l*64 + lr*8];
  sx8 Qf1 = *(const sx8*)&qhb[(size_t)qrow_l*64 + 32 + lr*8];

  __shared__ short Kl[2][64][64];      // 16KB, XOR-swizzled K staging
  __shared__ short pst[4][16][72];     // 9KB, per-wave P tile (144B rows)

  int idx0 = w*64 + l;
  int idx1 = 256 + w*64 + l;
  int rA = idx0>>3, oA = idx0&7, rB = idx1>>3, oB = idx1&7;
  int ntile = qt + 1;

  // ---- metered masked-tail fill state: rows 16 x chunks of 1KB from fs ----
  int fs = ((kend + 31) >> 5) << 5;
  int NCH = (NL - fs + 255) >> 8;      // 1KB chunks per row (0 if none)
  int frow = (NCH > 0) ? 0 : 16;
  int fch = 0;
  fx4 fz = (fx4)0.0f;
  auto fill_step = [&](int budget){
    while (budget > 0 && frow < 16){
      int c2 = fs + fch*256 + l*4;
      if (c2 < NL)
        __builtin_nontemporal_store(fz, (fx4*)&arow[(size_t)(qrow0+frow)*NL + c2]);
      if (++fch == NCH){ fch = 0; ++frow; }
      --budget;
    }
  };

  // ================= pass 1: denominators (+ metered fill) =================
  {
    sx8 ka = *(const sx8*)&khb[(size_t)rA*64 + oA*8];
    sx8 kb = *(const sx8*)&khb[(size_t)rB*64 + oB*8];
    *(sx8*)&Kl[0][rA][(oA^(rA&7))*8] = ka;
    *(sx8*)&Kl[0][rB][(oB^(rB&7))*8] = kb;
  }
  lds_barrier();

  float ls = 0.0f;
  int buf = 0;
  #pragma unroll 1
  for (int t=0; t<ntile; t++){
    bool have_next = (t+1) < ntile;
    sx8 ka, kb;
    if (have_next){
      int nb = (t+1)*64;
      ka = *(const sx8*)&khb[(size_t)(nb+rA)*64 + oA*8];
      kb = *(const sx8*)&khb[(size_t)(nb+rB)*64 + oB*8];
    }
    bool diag = (t == qt);
    #pragma unroll
    for (int kn=0; kn<4; kn++){
      if (diag && kn > w) continue;
      int rk = kn*16 + lc;
      sx8 k0 = *(const sx8*)&Kl[buf][rk][((lr  ^(rk&7))*8)];
      sx8 k1 = *(const sx8*)&Kl[buf][rk][(((lr+4)^(rk&7))*8)];
      fx4 s2 = (fx4)0.0f;
      s2 = __builtin_amdgcn_mfma_f32_16x16x32_bf16(k0, Qf0, s2, 0,0,0);
      s2 = __builtin_amdgcn_mfma_f32_16x16x32_bf16(k1, Qf1, s2, 0,0,0);
      if (!diag || kn < w) {
        ls += (ex2(s2[0]) + ex2(s2[1])) + (ex2(s2[2]) + ex2(s2[3]));
      } else {
        int key0 = t*64 + kn*16 + lr*4;
        #pragma unroll
        for (int r=0;r<4;r++)
          ls += (key0 + r <= qrow_l) ? ex2(s2[r]) : 0.0f;
      }
    }
    fill_step(3);                        // metered: queue stays shallow
    if (have_next){
      int nbuf = buf ^ 1;
      *(sx8*)&Kl[nbuf][rA][(oA^(rA&7))*8] = ka;
      *(sx8*)&Kl[nbuf][rB][(oB^(rB&7))*8] = kb;
    }
    lds_barrier();
    buf ^= 1;
  }
  ls += __shfl_xor(ls, 16, 64);
  ls += __shfl_xor(ls, 32, 64);
  float inv = 1.0f / ls;

  // flush any remaining fill (small-qt blocks have more fill than iters)
  fill_step(1<<30);

  // ================= pass 2: P tiles + PV + contiguous stores =============
  {
    sx8 ka = *(const sx8*)&khb[(size_t)rA*64 + oA*8];
    sx8 kb = *(const sx8*)&khb[(size_t)rB*64 + oB*8];
    *(sx8*)&Kl[0][rA][(oA^(rA&7))*8] = ka;
    *(sx8*)&Kl[0][rB][(oB^(rB&7))*8] = kb;
  }
  lds_barrier();

  fx4 O[4];
  #pragma unroll
  for (int n=0;n<4;n++) O[n] = (fx4)0.0f;

  int srow = l>>4, scol = l&15;          // store-phase lane mapping

  buf = 0;
  #pragma unroll 1
  for (int t=0; t<ntile; t++){
    int tb = t*64;
    bool have_next = (t+1) < ntile;
    sx8 ka, kb;
    if (have_next){
      int nb = tb + 64;
      ka = *(const sx8*)&khb[(size_t)(nb+rA)*64 + oA*8];
      kb = *(const sx8*)&khb[(size_t)(nb+rB)*64 + oB*8];
    }
    // V fragments for this tile: direct global loads (L2-local),
    // issued up front so latency hides under QK+exp.
    sx8 Vv[8];
    #pragma unroll
    for (int t2=0;t2<2;t2++)
      #pragma unroll
      for (int n=0;n<4;n++)
        Vv[t2*4+n] = *(const sx8*)&vtb[(size_t)(n*16+lc)*NL + tb + t2*32 + lr*8];

    bool diag = (t == qt);
    #pragma unroll
    for (int kn=0; kn<4; kn++){
      fx4 p;
      if (!diag || kn <= w) {
        int rk = kn*16 + lc;
        sx8 k0 = *(const sx8*)&Kl[buf][rk][((lr  ^(rk&7))*8)];
        sx8 k1 = *(const sx8*)&Kl[buf][rk][(((lr+4)^(rk&7))*8)];
        fx4 s2 = (fx4)0.0f;
        s2 = __builtin_amdgcn_mfma_f32_16x16x32_bf16(k0, Qf0, s2, 0,0,0);
        s2 = __builtin_amdgcn_mfma_f32_16x16x32_bf16(k1, Qf1, s2, 0,0,0);
        if (!diag || kn < w) {
          #pragma unroll
          for (int r=0;r<4;r++) p[r] = ex2(s2[r]) * inv;
        } else {
          int key0 = tb + kn*16 + lr*4;
          #pragma unroll
          for (int r=0;r<4;r++)
            p[r] = (key0 + r <= qrow_l) ? ex2(s2[r]) * inv : 0.0f;
        }
      } else {
        p = (fx4)0.0f;
      }
      sx4 pbv;
      #pragma unroll
      for (int r=0;r<4;r++) pbv[r] = f2bf(p[r]);
      *(sx4*)&pst[w][lc][kn*16 + lr*4] = pbv;
      if (kn & 1){
        sx8 pf = *(const sx8*)&pst[w][lc][(kn>>1)*32 + lr*8];
        #pragma unroll
        for (int n=0;n<4;n++)
          O[n] = __builtin_amdgcn_mfma_f32_16x16x32_bf16(pf, Vv[(kn>>1)*4+n], O[n], 0,0,0);
      }
    }
    // stream tile: 4 instrs x (4 rows x 256B contiguous) per wave
    #pragma unroll
    for (int jj=0;jj<4;jj++){
      int rr = jj*4 + srow;
      sx4 pb4 = *(const sx4*)&pst[w][rr][scol*4];
      fx4 o;
      #pragma unroll
      for (int i=0;i<4;i++) o[i] = bf2f(pb4[i]);
      __builtin_nontemporal_store(o, (fx4*)&arow[(size_t)(qrow0+rr)*NL + tb + scol*4]);
    }
    if (have_next){
      int nbuf = buf ^ 1;
      *(sx8*)&Kl[nbuf][rA][(oA^(rA&7))*8] = ka;
      *(sx8*)&Kl[nbuf][rB][(oB^(rB&7))*8] = kb;
    }
    lds_barrier();
    buf ^= 1;
  }

  int bb = bh>>4, hh = bh&15;
  #pragma unroll
  for (int n=0;n<4;n++)
    #pragma unroll
    for (int r=0;r<4;r++)
      ao[((size_t)bb*NL + qrow0 + lr*4 + r)*1024 + hh*64 + n*16 + lc] = f2bf(O[n][r]);
}

// ---------------------------------------------------------------------------
// LayerNorm over D=1024 per row. grid 4096, block 256.
// ---------------------------------------------------------------------------
__global__ __launch_bounds__(256) void ln_kernel(
    const float* __restrict__ preln, const float* __restrict__ gamma,
    const float* __restrict__ beta, float* __restrict__ out)
{
  int row = blockIdx.x, tid = threadIdx.x;
  fx4 x = *(const fx4*)&preln[(size_t)row*1024 + tid*4];
  float s  = x[0]+x[1]+x[2]+x[3];
  float sq = x[0]*x[0]+x[1]*x[1]+x[2]*x[2]+x[3]*x[3];
  #pragma unroll
  for (int off=1; off<64; off<<=1){
    s  += __shfl_xor(s,  off, 64);
    sq += __shfl_xor(sq, off, 64);
  }
  __shared__ float rs[4], rq[4];
  int w = tid>>6, l = tid&63;
  if (l==0){ rs[w]=s; rq[w]=sq; }
  __syncthreads();
  s  = rs[0]+rs[1]+rs[2]+rs[3];
  sq = rq[0]+rq[1]+rq[2]+rq[3];
  float mean = s*(1.0f/1024.0f);
  float var  = sq*(1.0f/1024.0f) - mean*mean;
  float rstd = rsqrtf(var + 1e-6f);
  fx4 g = *(const fx4*)&gamma[tid*4];
  fx4 b = *(const fx4*)&beta[tid*4];
  fx4 y;
  #pragma unroll
  for (int i=0;i<4;i++) y[i] = (x[i]-mean)*rstd*g[i] + b[i];
  *(fx4*)&out[(size_t)row*1024 + tid*4] = y;
}

// ---------------------------------------------------------------------------
extern "C" void kernel_launch(void* const* d_in, const int* in_sizes, int n_in,
                              void* d_out, int out_size, void* d_ws, size_t ws_size,
                              hipStream_t stream) {
  const float* q    = (const float*)d_in[0];
  const float* k    = (const float*)d_in[1];
  const float* v    = (const float*)d_in[2];
  const float* Wq   = (const float*)d_in[3];
  const float* Wk   = (const float*)d_in[4];
  const float* Wv   = (const float*)d_in[5];
  const float* Wfc  = (const float*)d_in[6];
  const float* gamma= (const float*)d_in[7];
  const float* beta = (const float*)d_in[8];
  // d_in[9] = mask: guaranteed causal tril by setup; causality applied structurally.

  float* out  = (float*)d_out;
  float* attn = out + (size_t)NB*NL*ND;

  char* ws = (char*)d_ws;
  short* wt    = (short*)(ws);                    // 8MB  [4x 1024^2 bf16]
  short* qb    = (short*)(ws + ((size_t) 8<<20)); // 8MB
  short* kb    = (short*)(ws + ((size_t)16<<20)); // 8MB
  short* vb    = (short*)(ws + ((size_t)24<<20)); // 8MB
  short* qh    = (short*)(ws + ((size_t)32<<20)); // 8MB
  short* kh    = (short*)(ws + ((size_t)40<<20)); // 8MB
  short* vtb   = (short*)(ws + ((size_t)48<<20)); // 8MB
  short* ao    = (short*)(ws + ((size_t)56<<20)); // 8MB
  float* preln = (float*)(ws + ((size_t) 8<<20)); // 16MB, aliases qb+kb (dead)

  wt_kernel<<<dim3(16,16,4), 256, 0, stream>>>(Wq, Wk, Wv, Wfc, wt);
  cast_kernel<<<dim3(2048,3), 256, 0, stream>>>(q, k, v, qb, kb, vb);
  gemm_kernel<<<dim3(8,32,3), 256, 0, stream>>>(qb,kb,vb,ao, q, wt, qh,kh,vtb, preln, 0);
  attn_kernel<<<1024, 256, 0, stream>>>(qh, kh, vtb, ao, attn);
  gemm_kernel<<<dim3(8,32,1), 256, 0, stream>>>(qb,kb,vb,ao, q, wt, qh,kh,vtb, preln, 3);
  ln_kernel<<<4096, 256, 0, stream>>>(preln, gamma, beta, out);
}

// Round 20
// 248.995 us; speedup vs baseline: 1.0439x; 1.0439x over previous
//
#include <hip/hip_runtime.h>
#include <hip/hip_bf16.h>

// Problem dims
#define NB 2
#define NL 2048
#define ND 1024
#define NH 16
#define NDK 64

typedef float fx4 __attribute__((ext_vector_type(4)));
typedef short sx8 __attribute__((ext_vector_type(8)));
typedef short sx4 __attribute__((ext_vector_type(4)));

static __device__ __forceinline__ short f2bf(float x) {
  __hip_bfloat16 h = __float2bfloat16(x);
  short s;
  __builtin_memcpy(&s, &h, 2);
  return s;
}

static __device__ __forceinline__ float bf2f(short s) {
  unsigned u = ((unsigned)(unsigned short)s) << 16;
  float f;
  __builtin_memcpy(&f, &u, 4);
  return f;
}

// 2^x via the HW transcendental unit
static __device__ __forceinline__ float ex2(float x) {
  float r; asm("v_exp_f32 %0, %1" : "=v"(r) : "v"(x)); return r;
}

// Barrier without vmcnt drain (LDS ordering only).
static __device__ __forceinline__ void lds_barrier() {
  __asm__ volatile("s_waitcnt lgkmcnt(0)" ::: "memory");
  __builtin_amdgcn_s_barrier();
}

// ---------------------------------------------------------------------------
// Transpose+cast: W[k][n] f32 -> WT[n][k] bf16 for Wq,Wk,Wv,Wfc.
// Wq additionally folds the (1/sqrt(dk))*log2(e) softmax scale.
// grid (16,16,4), block 256
// ---------------------------------------------------------------------------
__global__ __launch_bounds__(256) void wt_kernel(
    const float* __restrict__ Wq, const float* __restrict__ Wk,
    const float* __restrict__ Wv, const float* __restrict__ Wfc,
    short* __restrict__ wt)
{
  const float* W = (blockIdx.z==0)?Wq:(blockIdx.z==1)?Wk:(blockIdx.z==2)?Wv:Wfc;
  float sc = (blockIdx.z==0) ? 0.18033688011112042f : 1.0f;
  short* out = wt + (size_t)blockIdx.z*1024*1024;
  int n0 = blockIdx.x*64, k0 = blockIdx.y*64;
  __shared__ float t[64][65];
  int tid = threadIdx.x;
  int kr = tid>>2, ns = (tid&3)*16;
  #pragma unroll
  for (int i=0;i<4;i++){
    fx4 v = *(const fx4*)(W + (size_t)(k0+kr)*1024 + n0 + ns + i*4);
    t[kr][ns+i*4+0]=v[0]; t[kr][ns+i*4+1]=v[1];
    t[kr][ns+i*4+2]=v[2]; t[kr][ns+i*4+3]=v[3];
  }
  __syncthreads();
  int nr = tid>>2, ks = (tid&3)*16;
  sx8 o0,o1;
  #pragma unroll
  for (int i=0;i<8;i++){ o0[i]=f2bf(t[ks+i][nr]*sc); o1[i]=f2bf(t[ks+8+i][nr]*sc); }
  *(sx8*)(out + (size_t)(n0+nr)*1024 + k0 + ks)     = o0;
  *(sx8*)(out + (size_t)(n0+nr)*1024 + k0 + ks + 8) = o1;
}

// ---------------------------------------------------------------------------
// cast_kernel: q/k/v f32 [4096][1024] -> bf16. grid (2048,3), block 256.
// ---------------------------------------------------------------------------
__global__ __launch_bounds__(256) void cast_kernel(
    const float* __restrict__ q, const float* __restrict__ k,
    const float* __restrict__ v, short* __restrict__ qb,
    short* __restrict__ kb, short* __restrict__ vb)
{
  const float* src = (blockIdx.y==0)?q:(blockIdx.y==1)?k:v;
  short* dst = (blockIdx.y==0)?qb:(blockIdx.y==1)?kb:vb;
  size_t base = ((size_t)blockIdx.x*256 + threadIdx.x)*8;
  fx4 a = *(const fx4*)(src+base), b = *(const fx4*)(src+base+4);
  sx8 o;
  o[0]=f2bf(a[0]); o[1]=f2bf(a[1]); o[2]=f2bf(a[2]); o[3]=f2bf(a[3]);
  o[4]=f2bf(b[0]); o[5]=f2bf(b[1]); o[6]=f2bf(b[2]); o[7]=f2bf(b[3]);
  *(sx8*)(dst+base) = o;
}

// ---------------------------------------------------------------------------
// GEMM: C[4096x1024] = A(bf16) @ WT^T, 128x128 tile, BK=64, m97 structure:
// global_load_lds width-16 both sides, linear LDS, 2-barrier loop.
// mode 0: A=qb -> QH bf16 [B,H,L,64] (scale pre-folded into wt)
// mode 1: A=kb -> KH bf16 [B,H,L,64]
// mode 2: A=vb -> VT bf16 [B,H,64,L]
// mode 3: A=ao -> preLN f32 = C + residual(q)
// grid (8, 32, nz), block 256 (4 waves, 2x2 of 64x64)
// ---------------------------------------------------------------------------
__global__ __launch_bounds__(256) void gemm_kernel(
    const short* __restrict__ qb, const short* __restrict__ kb,
    const short* __restrict__ vb, const short* __restrict__ ao,
    const float* __restrict__ q, const short* __restrict__ wt,
    short* __restrict__ qh, short* __restrict__ kh, short* __restrict__ vtb,
    float* __restrict__ preln, int mode_base)
{
  int mode = mode_base + blockIdx.z;
  const short* Ab = (mode==0)?qb:(mode==1)?kb:(mode==2)?vb:ao;
  const short* Bw = wt + (size_t)mode*1048576;
  int m0 = blockIdx.y*128, n0 = blockIdx.x*128;
  __shared__ short Al[128*64];
  __shared__ short Bl[128*64];
  int tid = threadIdx.x;
  int w = tid>>6, l = tid&63, lr = l>>4, lc = l&15;
  int wm = w>>1, wn = w&1;
  int grow = l>>3, gcol = (l&7)*8;          // granule lane mapping

  fx4 acc[4][4];
  #pragma unroll
  for (int i=0;i<4;i++)
    #pragma unroll
    for (int j=0;j<4;j++) acc[i][j] = (fx4)0.0f;

  for (int kb2=0; kb2<1024; kb2+=64) {
    #pragma unroll
    for (int p=0;p<4;p++){
      int rb = w*32 + p*8;
      __builtin_amdgcn_global_load_lds(
        (const __attribute__((address_space(1))) int*)(Ab + (size_t)(m0+rb+grow)*1024 + kb2 + gcol),
        (__attribute__((address_space(3))) int*)&Al[rb*64], 16, 0, 0);
      __builtin_amdgcn_global_load_lds(
        (const __attribute__((address_space(1))) int*)(Bw + (size_t)(n0+rb+grow)*1024 + kb2 + gcol),
        (__attribute__((address_space(3))) int*)&Bl[rb*64], 16, 0, 0);
    }
    __syncthreads();
    #pragma unroll
    for (int kk=0;kk<2;kk++){
      sx8 af[4], bfr[4];
      int oct = kk*4 + lr;
      #pragma unroll
      for (int i=0;i<4;i++){
        af[i]  = *(const sx8*)&Al[(wm*64 + i*16 + lc)*64 + oct*8];
        bfr[i] = *(const sx8*)&Bl[(wn*64 + i*16 + lc)*64 + oct*8];
      }
      #pragma unroll
      for (int i=0;i<4;i++)
        #pragma unroll
        for (int j=0;j<4;j++)
          acc[i][j] = __builtin_amdgcn_mfma_f32_16x16x32_bf16(af[i], bfr[j], acc[i][j], 0,0,0);
    }
    __syncthreads();
  }

  #pragma unroll
  for (int i=0;i<4;i++){
    int mrow0 = m0 + wm*64 + i*16 + lr*4;
    #pragma unroll
    for (int j=0;j<4;j++){
      int n = n0 + wn*64 + j*16 + lc;
      if (mode<=1) {
        short* dst = (mode==0)?qh:kh;
        int hh = n>>6, d = n&63;
        #pragma unroll
        for (int r=0;r<4;r++){
          int mr = mrow0 + r; int bb = mr>>11, lp = mr&2047;
          dst[((size_t)(bb*16+hh)*2048 + lp)*64 + d] = f2bf(acc[i][j][r]);
        }
      } else if (mode==2) {
        int hh = n>>6, d = n&63;
        int bb = mrow0>>11, lp = mrow0&2047;
        sx4 pv;
        #pragma unroll
        for (int r=0;r<4;r++) pv[r] = f2bf(acc[i][j][r]);
        *(sx4*)&vtb[((size_t)(bb*16+hh)*64 + d)*2048 + lp] = pv;
      } else {
        #pragma unroll
        for (int r=0;r<4;r++){
          int mr = mrow0 + r;
          preln[(size_t)mr*1024 + n] = acc[i][j][r] + q[(size_t)mr*1024 + n];
        }
      }
    }
  }
}

// ---------------------------------------------------------------------------
// Fused attention (best-known, R18): 1-D grid 1024, XCD-local bh mapping
// (lin&7 = XCD; 4 bh x 32 vq per XCD -> K/V working set 2MB <= 4MB XCD L2).
// Per-CU balance: g=((vq>>3)+s)&3 -> qt in {r,15-r,16+r,31-r}, sum 62.
// Pass 1: denominators (K dbuf XOR-swizzled LDS). Between passes: masked-
// tail zero fill (the only point where the store queue is naturally empty).
// Pass 2: P tiles in pst[16][72] + PV (V direct from L2) + 256B-contiguous
// NT streams. lds_barrier only (no vmcnt drain). grid (1024), block 256.
// ---------------------------------------------------------------------------
__global__ __launch_bounds__(256) void attn_kernel(
    const short* __restrict__ qh, const short* __restrict__ kh,
    const short* __restrict__ vt, short* __restrict__ ao,
    float* __restrict__ attn)
{
  int lin = blockIdx.x;
  int c = lin & 7, m = lin >> 3;
  int s = m >> 5, vq = m & 31;
  int bh = c*4 + s;
  int r8 = vq & 7, g = ((vq >> 3) + s) & 3;
  int qt = (g==0) ? r8 : (g==1) ? (15-r8) : (g==2) ? (16+r8) : (31-r8);
  int qbase = qt*64;
  int tid = threadIdx.x, w = tid>>6, l = tid&63, lr = l>>4, lc = l&15;
  int qrow0 = qbase + w*16;
  int qrow_l = qrow0 + lc;
  int kend = qrow0 + 16;

  float* arow = attn + (size_t)bh*NL*NL;
  const short* qhb = qh + (size_t)bh*NL*64;
  const short* khb = kh + (size_t)bh*NL*64;
  const short* vtb = vt + (size_t)bh*64*NL;

  sx8 Qf0 = *(const sx8*)&qhb[(size_t)qrow_l*64 + lr*8];
  sx8 Qf1 = *(const sx8*)&qhb[(size_t)qrow_l*64 + 32 + lr*8];

  __shared__ short Kl[2][64][64];      // 16KB, XOR-swizzled K staging
  __shared__ short pst[4][16][72];     // 9KB, per-wave P tile (144B rows)

  int idx0 = w*64 + l;
  int idx1 = 256 + w*64 + l;
  int rA = idx0>>3, oA = idx0&7, rB = idx1>>3, oB = idx1&7;
  int ntile = qt + 1;

  // ================= pass 1: denominators =================
  {
    sx8 ka = *(const sx8*)&khb[(size_t)rA*64 + oA*8];
    sx8 kb = *(const sx8*)&khb[(size_t)rB*64 + oB*8];
    *(sx8*)&Kl[0][rA][(oA^(rA&7))*8] = ka;
    *(sx8*)&Kl[0][rB][(oB^(rB&7))*8] = kb;
  }
  lds_barrier();

  float ls = 0.0f;
  int buf = 0;
  #pragma unroll 1
  for (int t=0; t<ntile; t++){
    bool have_next = (t+1) < ntile;
    sx8 ka, kb;
    if (have_next){
      int nb = (t+1)*64;
      ka = *(const sx8*)&khb[(size_t)(nb+rA)*64 + oA*8];
      kb = *(const sx8*)&khb[(size_t)(nb+rB)*64 + oB*8];
    }
    bool diag = (t == qt);
    #pragma unroll
    for (int kn=0; kn<4; kn++){
      if (diag && kn > w) continue;
      int rk = kn*16 + lc;
      sx8 k0 = *(const sx8*)&Kl[buf][rk][((lr  ^(rk&7))*8)];
      sx8 k1 = *(const sx8*)&Kl[buf][rk][(((lr+4)^(rk&7))*8)];
      fx4 s2 = (fx4)0.0f;
      s2 = __builtin_amdgcn_mfma_f32_16x16x32_bf16(k0, Qf0, s2, 0,0,0);
      s2 = __builtin_amdgcn_mfma_f32_16x16x32_bf16(k1, Qf1, s2, 0,0,0);
      if (!diag || kn < w) {
        ls += (ex2(s2[0]) + ex2(s2[1])) + (ex2(s2[2]) + ex2(s2[3]));
      } else {
        int key0 = t*64 + kn*16 + lr*4;
        #pragma unroll
        for (int r=0;r<4;r++)
          ls += (key0 + r <= qrow_l) ? ex2(s2[r]) : 0.0f;
      }
    }
    if (have_next){
      int nbuf = buf ^ 1;
      *(sx8*)&Kl[nbuf][rA][(oA^(rA&7))*8] = ka;
      *(sx8*)&Kl[nbuf][rB][(oB^(rB&7))*8] = kb;
    }
    lds_barrier();
    buf ^= 1;
  }
  ls += __shfl_xor(ls, 16, 64);
  ls += __shfl_xor(ls, 32, 64);
  float inv = 1.0f / ls;

  // masked-tail zero fill for this wave's 16 rows: [ceil32(kend), NL)
  {
    int fs = ((kend + 31) >> 5) << 5;
    fx4 z = (fx4)0.0f;
    #pragma unroll 1
    for (int r=0; r<16; r++){
      float* rp = &arow[(size_t)(qrow0+r)*NL];
      for (int c2 = fs + l*4; c2 < NL; c2 += 256)
        __builtin_nontemporal_store(z, (fx4*)&rp[c2]);
    }
  }

  // ================= pass 2: P tiles + PV + contiguous stores =============
  {
    sx8 ka = *(const sx8*)&khb[(size_t)rA*64 + oA*8];
    sx8 kb = *(const sx8*)&khb[(size_t)rB*64 + oB*8];
    *(sx8*)&Kl[0][rA][(oA^(rA&7))*8] = ka;
    *(sx8*)&Kl[0][rB][(oB^(rB&7))*8] = kb;
  }
  lds_barrier();

  fx4 O[4];
  #pragma unroll
  for (int n=0;n<4;n++) O[n] = (fx4)0.0f;

  int srow = l>>4, scol = l&15;          // store-phase lane mapping

  buf = 0;
  #pragma unroll 1
  for (int t=0; t<ntile; t++){
    int tb = t*64;
    bool have_next = (t+1) < ntile;
    sx8 ka, kb;
    if (have_next){
      int nb = tb + 64;
      ka = *(const sx8*)&khb[(size_t)(nb+rA)*64 + oA*8];
      kb = *(const sx8*)&khb[(size_t)(nb+rB)*64 + oB*8];
    }
    // V fragments for this tile: direct global loads (L2-local),
    // issued up front so latency hides under QK+exp.
    sx8 Vv[8];
    #pragma unroll
    for (int t2=0;t2<2;t2++)
      #pragma unroll
      for (int n=0;n<4;n++)
        Vv[t2*4+n] = *(const sx8*)&vtb[(size_t)(n*16+lc)*NL + tb + t2*32 + lr*8];

    bool diag = (t == qt);
    #pragma unroll
    for (int kn=0; kn<4; kn++){
      fx4 p;
      if (!diag || kn <= w) {
        int rk = kn*16 + lc;
        sx8 k0 = *(const sx8*)&Kl[buf][rk][((lr  ^(rk&7))*8)];
        sx8 k1 = *(const sx8*)&Kl[buf][rk][(((lr+4)^(rk&7))*8)];
        fx4 s2 = (fx4)0.0f;
        s2 = __builtin_amdgcn_mfma_f32_16x16x32_bf16(k0, Qf0, s2, 0,0,0);
        s2 = __builtin_amdgcn_mfma_f32_16x16x32_bf16(k1, Qf1, s2, 0,0,0);
        if (!diag || kn < w) {
          #pragma unroll
          for (int r=0;r<4;r++) p[r] = ex2(s2[r]) * inv;
        } else {
          int key0 = tb + kn*16 + lr*4;
          #pragma unroll
          for (int r=0;r<4;r++)
            p[r] = (key0 + r <= qrow_l) ? ex2(s2[r]) * inv : 0.0f;
        }
      } else {
        p = (fx4)0.0f;
      }
      sx4 pbv;
      #pragma unroll
      for (int r=0;r<4;r++) pbv[r] = f2bf(p[r]);
      *(sx4*)&pst[w][lc][kn*16 + lr*4] = pbv;
      if (kn & 1){
        sx8 pf = *(const sx8*)&pst[w][lc][(kn>>1)*32 + lr*8];
        #pragma unroll
        for (int n=0;n<4;n++)
          O[n] = __builtin_amdgcn_mfma_f32_16x16x32_bf16(pf, Vv[(kn>>1)*4+n], O[n], 0,0,0);
      }
    }
    // stream tile: 4 instrs x (4 rows x 256B contiguous) per wave
    #pragma unroll
    for (int jj=0;jj<4;jj++){
      int rr = jj*4 + srow;
      sx4 pb4 = *(const sx4*)&pst[w][rr][scol*4];
      fx4 o;
      #pragma unroll
      for (int i=0;i<4;i++) o[i] = bf2f(pb4[i]);
      __builtin_nontemporal_store(o, (fx4*)&arow[(size_t)(qrow0+rr)*NL + tb + scol*4]);
    }
    if (have_next){
      int nbuf = buf ^ 1;
      *(sx8*)&Kl[nbuf][rA][(oA^(rA&7))*8] = ka;
      *(sx8*)&Kl[nbuf][rB][(oB^(rB&7))*8] = kb;
    }
    lds_barrier();
    buf ^= 1;
  }

  int bb = bh>>4, hh = bh&15;
  #pragma unroll
  for (int n=0;n<4;n++)
    #pragma unroll
    for (int r=0;r<4;r++)
      ao[((size_t)bb*NL + qrow0 + lr*4 + r)*1024 + hh*64 + n*16 + lc] = f2bf(O[n][r]);
}

// ---------------------------------------------------------------------------
// LayerNorm over D=1024 per row. grid 4096, block 256.
// ---------------------------------------------------------------------------
__global__ __launch_bounds__(256) void ln_kernel(
    const float* __restrict__ preln, const float* __restrict__ gamma,
    const float* __restrict__ beta, float* __restrict__ out)
{
  int row = blockIdx.x, tid = threadIdx.x;
  fx4 x = *(const fx4*)&preln[(size_t)row*1024 + tid*4];
  float s  = x[0]+x[1]+x[2]+x[3];
  float sq = x[0]*x[0]+x[1]*x[1]+x[2]*x[2]+x[3]*x[3];
  #pragma unroll
  for (int off=1; off<64; off<<=1){
    s  += __shfl_xor(s,  off, 64);
    sq += __shfl_xor(sq, off, 64);
  }
  __shared__ float rs[4], rq[4];
  int w = tid>>6, l = tid&63;
  if (l==0){ rs[w]=s; rq[w]=sq; }
  __syncthreads();
  s  = rs[0]+rs[1]+rs[2]+rs[3];
  sq = rq[0]+rq[1]+rq[2]+rq[3];
  float mean = s*(1.0f/1024.0f);
  float var  = sq*(1.0f/1024.0f) - mean*mean;
  float rstd = rsqrtf(var + 1e-6f);
  fx4 g = *(const fx4*)&gamma[tid*4];
  fx4 b = *(const fx4*)&beta[tid*4];
  fx4 y;
  #pragma unroll
  for (int i=0;i<4;i++) y[i] = (x[i]-mean)*rstd*g[i] + b[i];
  *(fx4*)&out[(size_t)row*1024 + tid*4] = y;
}

// ---------------------------------------------------------------------------
extern "C" void kernel_launch(void* const* d_in, const int* in_sizes, int n_in,
                              void* d_out, int out_size, void* d_ws, size_t ws_size,
                              hipStream_t stream) {
  const float* q    = (const float*)d_in[0];
  const float* k    = (const float*)d_in[1];
  const float* v    = (const float*)d_in[2];
  const float* Wq   = (const float*)d_in[3];
  const float* Wk   = (const float*)d_in[4];
  const float* Wv   = (const float*)d_in[5];
  const float* Wfc  = (const float*)d_in[6];
  const float* gamma= (const float*)d_in[7];
  const float* beta = (const float*)d_in[8];
  // d_in[9] = mask: guaranteed causal tril by setup; causality applied structurally.

  float* out  = (float*)d_out;
  float* attn = out + (size_t)NB*NL*ND;

  char* ws = (char*)d_ws;
  short* wt    = (short*)(ws);                    // 8MB  [4x 1024^2 bf16]
  short* qb    = (short*)(ws + ((size_t) 8<<20)); // 8MB
  short* kb    = (short*)(ws + ((size_t)16<<20)); // 8MB
  short* vb    = (short*)(ws + ((size_t)24<<20)); // 8MB
  short* qh    = (short*)(ws + ((size_t)32<<20)); // 8MB
  short* kh    = (short*)(ws + ((size_t)40<<20)); // 8MB
  short* vtb   = (short*)(ws + ((size_t)48<<20)); // 8MB
  short* ao    = (short*)(ws + ((size_t)56<<20)); // 8MB
  float* preln = (float*)(ws + ((size_t) 8<<20)); // 16MB, aliases qb+kb (dead)

  wt_kernel<<<dim3(16,16,4), 256, 0, stream>>>(Wq, Wk, Wv, Wfc, wt);
  cast_kernel<<<dim3(2048,3), 256, 0, stream>>>(q, k, v, qb, kb, vb);
  gemm_kernel<<<dim3(8,32,3), 256, 0, stream>>>(qb,kb,vb,ao, q, wt, qh,kh,vtb, preln, 0);
  attn_kernel<<<1024, 256, 0, stream>>>(qh, kh, vtb, ao, attn);
  gemm_kernel<<<dim3(8,32,1), 256, 0, stream>>>(qb,kb,vb,ao, q, wt, qh,kh,vtb, preln, 3);
  ln_kernel<<<4096, 256, 0, stream>>>(preln, gamma, beta, out);
}